// Round 15
// baseline (441.191 us; speedup 1.0000x reference)
//
#include <hip/hip_runtime.h>
#include <hip/hip_bf16.h>

// Problem constants
#define T_TOK 4096          // B*S tokens
#define D_DIM 1024
#define H_DIM 4096
#define E_EXP 8
#define K_TOP 2
#define TP (T_TOK * K_TOP)  // 8192 (token, expert) pairs
#define BM 128
#define BN 128
#define BKS 32              // K-step (shorts) -- r2/r5-verified
#define MAX_TILES 72

typedef __attribute__((ext_vector_type(8))) short bf16x8;
typedef __attribute__((ext_vector_type(4))) float f32x4;
typedef __attribute__((ext_vector_type(8))) unsigned short u16x8;
typedef __attribute__((ext_vector_type(4))) unsigned short u16x4;

// LDS chunk swizzle for the GEMMs (verified r2..r14: 0 conflicts)
#define SWZ(row, chunk) ((chunk) ^ (((row) >> 1) & 3))

static __device__ __forceinline__ void gload16(const unsigned short* g, unsigned short* l) {
  __builtin_amdgcn_global_load_lds((const __attribute__((address_space(1))) void*)g,
                                   (__attribute__((address_space(3))) void*)l, 16, 0, 0);
}

static __device__ __forceinline__ unsigned short f2bf(float f) {
  unsigned int bits = __float_as_uint(f);
  unsigned int lsb = (bits >> 16) & 1u;
  bits += 0x7fffu + lsb;
  return (unsigned short)(bits >> 16);
}

static __device__ __forceinline__ float gelu_fast(float u) {
  float z = u * (0.79788456080286536f + 0.0356774081f * u * u);
  float t = __expf(-2.f * z);
  return u / (1.f + t);
}

// ---------------- r15 transpose body: 128x128 tile, bf16 LDS [128][130] ----------------
// Read runs 512B (vs 256), write runs 256B (vs 128) -> ~2x DRAM efficiency.
// tile stride 130 u16: row-word-stride 65 (odd -> read-phase scalar stores 2-way free);
// write-phase 8-row packed reads: 520 = 8 mod 32 -> ~4-way (minor phase).
static __device__ __forceinline__ void transpose128_body(
    const float* __restrict__ s, unsigned short* __restrict__ d, int R, int C,
    int c0, int r0, unsigned short* tile_b, int tid) {
#pragma unroll
  for (int p = 0; p < 16; ++p) {
    int u = tid + 256 * p;
    int row = u >> 5, c4 = u & 31;            // per wave: 2 rows x 512B coalesced
    float4 v = *(const float4*)(&s[(size_t)(r0 + row) * C + c0 + c4 * 4]);
    int base = row * 130 + c4 * 4;
    tile_b[base + 0] = f2bf(v.x);
    tile_b[base + 1] = f2bf(v.y);
    tile_b[base + 2] = f2bf(v.z);
    tile_b[base + 3] = f2bf(v.w);
  }
  __syncthreads();
#pragma unroll
  for (int p = 0; p < 8; ++p) {
    int u = tid + 256 * p;
    int c = u >> 4, rq = u & 15;              // 16 lanes x 16B = 256B per output row
    u16x8 o;
#pragma unroll
    for (int q = 0; q < 8; ++q) o[q] = tile_b[(rq * 8 + q) * 130 + c];
    *(u16x8*)(&d[(size_t)(c0 + c) * R + r0 + rq * 8]) = o;
  }
}

// =====================================================================
// FRONT: fused {gating (blocks 0..1023)} + {W1 transpose, 128x128 tiles}.
// W2 transpose moved into ffn1_kernel's grid (overlaps GEMM's idle BW).
// =====================================================================
#define NGATE (T_TOK / 4)                              // 1024
#define NTRW1 ((H_DIM / 128) * (D_DIM / 128) * E_EXP)  // 32*8*8 = 2048
#define NTRW2 ((D_DIM / 128) * (H_DIM / 128) * E_EXP)  // 8*32*8 = 2048

__global__ __launch_bounds__(256) void front_kernel(
    const float* __restrict__ W1, unsigned short* __restrict__ w1t,
    const float* __restrict__ x, const float* __restrict__ noise,
    const float* __restrict__ Wg, const float* __restrict__ bg,
    const float* __restrict__ Wn, const float* __restrict__ bn,
    int* __restrict__ tok_e, float* __restrict__ tok_w,
    float* __restrict__ gp_tok, int* __restrict__ counts,
    unsigned short* __restrict__ xb) {
  __shared__ unsigned short tile_b[128 * 130];  // 33.3KB, transpose blocks only
  int bid = blockIdx.x;
  const int tid = threadIdx.x;

  if (bid < NGATE) {
    // ---------------- gating body (r9/r10/r14-verified) ----------------
    const int lane = tid & 63, wid = tid >> 6;
    const int t = bid * 4 + wid;
    const float* xrow = x + (size_t)t * D_DIM;
    float ag[8] = {0, 0, 0, 0, 0, 0, 0, 0};
    float an[8] = {0, 0, 0, 0, 0, 0, 0, 0};
#pragma unroll 4
    for (int i = 0; i < 16; ++i) {
      int dd = i * 64 + lane;
      float xv = xrow[dd];
      xb[(size_t)t * D_DIM + dd] = f2bf(xv);        // fused x -> bf16
      const float4* g4 = (const float4*)(Wg + (size_t)dd * 8);
      const float4* n4 = (const float4*)(Wn + (size_t)dd * 8);
      float4 ga = g4[0], gb = g4[1], na = n4[0], nb = n4[1];
      ag[0] += xv * ga.x; ag[1] += xv * ga.y; ag[2] += xv * ga.z; ag[3] += xv * ga.w;
      ag[4] += xv * gb.x; ag[5] += xv * gb.y; ag[6] += xv * gb.z; ag[7] += xv * gb.w;
      an[0] += xv * na.x; an[1] += xv * na.y; an[2] += xv * na.z; an[3] += xv * na.w;
      an[4] += xv * nb.x; an[5] += xv * nb.y; an[6] += xv * nb.z; an[7] += xv * nb.w;
    }
#pragma unroll
    for (int e = 0; e < 8; ++e) {
      for (int off = 32; off > 0; off >>= 1) {
        ag[e] += __shfl_down(ag[e], off);
        an[e] += __shfl_down(an[e], off);
      }
    }
    if (lane == 0) {
      float logit[8], noisy[8];
#pragma unroll
      for (int e = 0; e < 8; ++e) {
        logit[e] = ag[e] + bg[e];
        float pre = an[e] + bn[e];
        float sp = fmaxf(pre, 0.f) + log1pf(expf(-fabsf(pre)));   // softplus, stable
        noisy[e] = logit[e] + noise[(size_t)t * 8 + e] * sp;
      }
      float mx = logit[0];
#pragma unroll
      for (int e = 1; e < 8; ++e) mx = fmaxf(mx, logit[e]);
      float s = 0.f, p[8];
#pragma unroll
      for (int e = 0; e < 8; ++e) { p[e] = expf(logit[e] - mx); s += p[e]; }
      float inv = 1.f / s;
#pragma unroll
      for (int e = 0; e < 8; ++e) gp_tok[(size_t)t * 8 + e] = p[e] * inv;
      // top-2 (strict > keeps lowest index on ties, matching lax.top_k)
      int i0 = 0; float v0 = noisy[0];
#pragma unroll
      for (int e = 1; e < 8; ++e) if (noisy[e] > v0) { v0 = noisy[e]; i0 = e; }
      int i1 = -1; float v1 = 0.f;
#pragma unroll
      for (int e = 0; e < 8; ++e) {
        if (e == i0) continue;
        if (i1 < 0 || noisy[e] > v1) { v1 = noisy[e]; i1 = e; }
      }
      float e1 = expf(v1 - v0);      // v0 >= v1
      float w0 = 1.f / (1.f + e1);
      float w1 = e1 * w0;
      tok_e[t * 2 + 0] = i0; tok_e[t * 2 + 1] = i1;
      tok_w[t * 2 + 0] = w0; tok_w[t * 2 + 1] = w1;
      atomicAdd(&counts[i0], 1);
      atomicAdd(&counts[i1], 1);
    }
    return;
  }
  bid -= NGATE;
  // ---------------- W1 transpose: [E][D][H] fp32 -> [E][H][D] bf16 ----------------
  const int bx = bid & 31, by = (bid >> 5) & 7, e = bid >> 8;   // C/128=32, R/128=8
  transpose128_body(W1 + (size_t)e * D_DIM * H_DIM,
                    w1t + (size_t)e * D_DIM * H_DIM,
                    D_DIM, H_DIM, bx * 128, by * 128, tile_b, tid);
}

// =====================================================================
// FINALIZE: fused scan + scatter (LDS cursors) + loss (r14-verified).
// =====================================================================
__global__ __launch_bounds__(256) void finalize_kernel(
    const int* __restrict__ counts, int4* __restrict__ tiles,
    int* __restrict__ ntiles,
    const int* __restrict__ tok_e, const float* __restrict__ tok_w,
    int* __restrict__ pair_token, float* __restrict__ pair_w,
    const float* __restrict__ gp_tok, float* __restrict__ out) {
  __shared__ int s_off[E_EXP];
  __shared__ int s_cur[E_EXP];
  __shared__ float red[256];
  const int tid = threadIdx.x;

  if (tid == 0) {
    int off = 0, nt = 0;
    for (int e = 0; e < E_EXP; ++e) {
      s_off[e] = off;
      int c = counts[e];
      for (int r = 0; r < c; r += BM) {
        tiles[nt] = make_int4(e, off + r, min(BM, c - r), 0);
        ++nt;
      }
      off += c;
    }
    *ntiles = nt;
  }
  if (tid < E_EXP) s_cur[tid] = 0;
  __syncthreads();

  for (int t = tid; t < T_TOK; t += 256) {
#pragma unroll
    for (int k = 0; k < 2; ++k) {
      int e = tok_e[t * 2 + k];
      int pos = atomicAdd(&s_cur[e], 1);
      int p = s_off[e] + pos;
      pair_token[p] = t;
      pair_w[p] = tok_w[t * 2 + k];
    }
  }

  float part[8] = {0, 0, 0, 0, 0, 0, 0, 0};
  for (int r = tid; r < T_TOK; r += 256) {
    const float* g = gp_tok + (size_t)r * 8;
#pragma unroll
    for (int e = 0; e < 8; ++e) part[e] += g[e];
  }
  float total[8];
#pragma unroll
  for (int e = 0; e < 8; ++e) {
    red[tid] = part[e];
    __syncthreads();
    for (int s = 128; s > 0; s >>= 1) {
      if (tid < s) red[tid] += red[tid + s];
      __syncthreads();
    }
    if (tid == 0) total[e] = red[0];
    __syncthreads();
  }
  if (tid == 0) {
    float ll = 0.f;
#pragma unroll
    for (int e = 0; e < 8; ++e)
      ll += ((float)counts[e] / (float)TP) * (total[e] / (float)T_TOK);
    out[(size_t)T_TOK * D_DIM] = ll * (float)E_EXP;
  }
}

// ---------------- FFN1 (+ fused W2 transpose blocks) ----------------
// GEMM body r6/r8/r10/r14-verified; blocks [0, NTRW2) transpose W2 (BW-bound,
// soaks the GEMM's idle memory pipe); w2t consumed by ffn2 (stream-ordered).
__global__ __launch_bounds__(256) void ffn1_kernel(
    const unsigned short* __restrict__ xb,    // [T][D] bf16
    const unsigned short* __restrict__ w1t,   // [E][H][D] bf16 (transposed)
    const float* __restrict__ b1,             // [E][H]
    const int* __restrict__ pair_token,       // [TP]
    const int4* __restrict__ tiles, const int* __restrict__ ntiles,
    unsigned short* __restrict__ hbuf,        // [TP][H] bf16
    const float* __restrict__ W2, unsigned short* __restrict__ w2t) {
  __shared__ unsigned short sh[16640];        // GEMM uses 16384; transpose uses 128*130
  const int tid = threadIdx.x;
  int bid = blockIdx.x;

  if (bid < NTRW2) {
    // W2 transpose: [E][H][D] fp32 -> [E][D][H] bf16
    const int bx = bid & 7, by = (bid >> 3) & 31, e = bid >> 8;  // C/128=8, R/128=32
    transpose128_body(W2 + (size_t)e * D_DIM * H_DIM,
                      w2t + (size_t)e * D_DIM * H_DIM,
                      H_DIM, D_DIM, bx * 128, by * 128, sh, tid);
    return;
  }
  bid -= NTRW2;

  const int NB = H_DIM / BN;                  // 32
  const int nwg = MAX_TILES * NB;             // 2304, %8==0
  int wg = (bid & 7) * (nwg >> 3) + (bid >> 3);   // bijective XCD chunking
  int tileId = wg / NB, nb = wg - tileId * NB;
  if (tileId >= *ntiles) return;
  int4 tl = tiles[tileId];
  const int e = tl.x, row0 = tl.y, rows = tl.z;
  const int n0 = nb * BN;

#define AS1(buf) (sh + (buf) * 4096)
#define BS1(buf) (sh + 8192 + (buf) * 4096)

  const int wid = tid >> 6, lane = tid & 63;
  const int sr = tid >> 2;
  const int sc = tid & 3;
  const int scz = SWZ(sr, sc) * 8;

  int r0a = row0 + sr;       if (r0a > TP - 1) r0a = TP - 1;
  int r1a = row0 + sr + 64;  if (r1a > TP - 1) r1a = TP - 1;
  const unsigned short* a0 = xb + (size_t)pair_token[r0a] * D_DIM + scz;
  const unsigned short* a1 = xb + (size_t)pair_token[r1a] * D_DIM + scz;
  const unsigned short* bp0 = w1t + ((size_t)e * H_DIM + (n0 + sr)) * D_DIM + scz;
  const unsigned short* bp1 = w1t + ((size_t)e * H_DIM + (n0 + sr + 64)) * D_DIM + scz;

  const int wbase = wid * 512;
  const int wr = wid >> 1, wc = wid & 1;
  const int lrow = lane & 15, lkc = lane >> 4;

  f32x4 acc[4][4] = {};

  auto stage = [&](int buf, int k0) {
    gload16(a0 + k0, AS1(buf) + wbase);
    gload16(a1 + k0, AS1(buf) + wbase + 2048);
    gload16(bp0 + k0, BS1(buf) + wbase);
    gload16(bp1 + k0, BS1(buf) + wbase + 2048);
  };
  auto compute_step = [&](int buf) {
    bf16x8 af[4], bfr[4];
#pragma unroll
    for (int m = 0; m < 4; ++m) {
      int r = wr * 64 + m * 16 + lrow;
      af[m] = *(const bf16x8*)(AS1(buf) + r * BKS + SWZ(r, lkc) * 8);
    }
#pragma unroll
    for (int n = 0; n < 4; ++n) {
      int r = wc * 64 + n * 16 + lrow;
      bfr[n] = *(const bf16x8*)(BS1(buf) + r * BKS + SWZ(r, lkc) * 8);
    }
#pragma unroll
    for (int m = 0; m < 4; ++m)
#pragma unroll
      for (int n = 0; n < 4; ++n)
        acc[m][n] = __builtin_amdgcn_mfma_f32_16x16x32_bf16(af[m], bfr[n], acc[m][n], 0, 0, 0);
  };

  const int NK = D_DIM / BKS;                 // 32
  stage(0, 0);
  stage(1, BKS);
  int cur = 0;
  for (int k = 0; k < NK - 1; ++k) {
    asm volatile("s_waitcnt vmcnt(4)" ::: "memory");
    __builtin_amdgcn_s_barrier();
    __builtin_amdgcn_sched_barrier(0);
    compute_step(cur);
    __builtin_amdgcn_sched_barrier(0);
    __builtin_amdgcn_s_barrier();
    if (k < NK - 2) stage(cur, (k + 2) * BKS);
    cur ^= 1;
  }
  asm volatile("s_waitcnt vmcnt(0)" ::: "memory");
  __builtin_amdgcn_s_barrier();
  __builtin_amdgcn_sched_barrier(0);
  compute_step(cur);

  // epilogue: gelu -> LDS [128][128] (chunk-XOR swizzled) -> coalesced stores
  __syncthreads();
#pragma unroll
  for (int n = 0; n < 4; ++n) {
    int clocal = wc * 64 + n * 16 + lrow;
    float bias = b1[(size_t)e * H_DIM + n0 + clocal];
    int chunk = clocal >> 3, within = clocal & 7;
#pragma unroll
    for (int m = 0; m < 4; ++m) {
#pragma unroll
      for (int j = 0; j < 4; ++j) {
        int rloc = wr * 64 + m * 16 + (lane >> 4) * 4 + j;
        float v = acc[m][n][j] + bias;
        sh[rloc * 128 + ((chunk ^ ((rloc >> 1) & 7)) * 8) + within] = f2bf(gelu_fast(v));
      }
    }
  }
  __syncthreads();
#pragma unroll
  for (int it = 0; it < 8; ++it) {
    int u = tid + 256 * it;
    int r = u >> 4, cg = u & 15;
    if (r < rows) {
      u16x8 v = *(const u16x8*)(&sh[r * 128 + ((cg ^ ((r >> 1) & 7)) * 8)]);
      *(u16x8*)(&hbuf[(size_t)(row0 + r) * H_DIM + n0 + cg * 8]) = v;
    }
  }
#undef AS1
#undef BS1
}

// ---------------- FFN2 (r8/r10/r14-verified) ----------------
__global__ __launch_bounds__(256) void ffn2_kernel(
    const unsigned short* __restrict__ hbuf,  // [TP][H] bf16
    const unsigned short* __restrict__ w2t,   // [E][D][H] bf16 (transposed)
    const float* __restrict__ b2,             // [E][D]
    const int* __restrict__ pair_token, const float* __restrict__ pair_w,
    const int4* __restrict__ tiles, const int* __restrict__ ntiles,
    float* __restrict__ out) {
  const int NB = D_DIM / BN;                  // 8
  const int nwg = MAX_TILES * NB;             // 576, %8==0
  int bid = blockIdx.x;
  int wg = (bid & 7) * (nwg >> 3) + (bid >> 3);
  int tileId = wg / NB, nb = wg - tileId * NB;
  if (tileId >= *ntiles) return;
  int4 tl = tiles[tileId];
  const int e = tl.x, row0 = tl.y, rows = tl.z;
  const int n0 = nb * BN;

  __shared__ unsigned short As[2][BM * BKS];
  __shared__ unsigned short Bs[2][BN * BKS];
  __shared__ int stok[BM];
  __shared__ float spw[BM];

  const int tid = threadIdx.x;
  if (tid < BM) {
    int rr = row0 + tid; if (rr > TP - 1) rr = TP - 1;
    stok[tid] = pair_token[rr];
    spw[tid] = pair_w[rr];
  }

  const int wid = tid >> 6, lane = tid & 63;
  const int sr = tid >> 2;
  const int sc = tid & 3;
  const int scz = SWZ(sr, sc) * 8;

  int r0a = row0 + sr;       if (r0a > TP - 1) r0a = TP - 1;
  int r1a = row0 + sr + 64;  if (r1a > TP - 1) r1a = TP - 1;
  const unsigned short* a0 = hbuf + (size_t)r0a * H_DIM + scz;
  const unsigned short* a1 = hbuf + (size_t)r1a * H_DIM + scz;
  const unsigned short* bp0 = w2t + ((size_t)e * D_DIM + (n0 + sr)) * H_DIM + scz;
  const unsigned short* bp1 = w2t + ((size_t)e * D_DIM + (n0 + sr + 64)) * H_DIM + scz;

  const int wbase = wid * 512;
  const int wr = wid >> 1, wc = wid & 1;
  const int lrow = lane & 15, lkc = lane >> 4;

  f32x4 acc[4][4] = {};

  auto stage = [&](int buf, int k0) {
    gload16(a0 + k0, &As[buf][wbase]);
    gload16(a1 + k0, &As[buf][wbase + 2048]);
    gload16(bp0 + k0, &Bs[buf][wbase]);
    gload16(bp1 + k0, &Bs[buf][wbase + 2048]);
  };
  auto compute_step = [&](int buf) {
    bf16x8 af[4], bfr[4];
#pragma unroll
    for (int m = 0; m < 4; ++m) {
      int r = wr * 64 + m * 16 + lrow;
      af[m] = *(const bf16x8*)(&As[buf][r * BKS + SWZ(r, lkc) * 8]);
    }
#pragma unroll
    for (int n = 0; n < 4; ++n) {
      int r = wc * 64 + n * 16 + lrow;
      bfr[n] = *(const bf16x8*)(&Bs[buf][r * BKS + SWZ(r, lkc) * 8]);
    }
#pragma unroll
    for (int m = 0; m < 4; ++m)
#pragma unroll
      for (int n = 0; n < 4; ++n)
        acc[m][n] = __builtin_amdgcn_mfma_f32_16x16x32_bf16(af[m], bfr[n], acc[m][n], 0, 0, 0);
  };

  const int NK = H_DIM / BKS;                 // 128
  stage(0, 0);
  stage(1, BKS);
  int cur = 0;
  for (int k = 0; k < NK - 1; ++k) {
    asm volatile("s_waitcnt vmcnt(4)" ::: "memory");
    __builtin_amdgcn_s_barrier();
    __builtin_amdgcn_sched_barrier(0);
    compute_step(cur);
    __builtin_amdgcn_sched_barrier(0);
    __builtin_amdgcn_s_barrier();
    if (k < NK - 2) stage(cur, (k + 2) * BKS);
    cur ^= 1;
  }
  asm volatile("s_waitcnt vmcnt(0)" ::: "memory");
  __builtin_amdgcn_s_barrier();
  __builtin_amdgcn_sched_barrier(0);
  compute_step(cur);

  const int colbase = n0 + wc * 64;
#pragma unroll
  for (int n = 0; n < 4; ++n) {
    int colg = colbase + n * 16 + lrow;
    float bias = b2[(size_t)e * D_DIM + colg];
#pragma unroll
    for (int m = 0; m < 4; ++m) {
      int rbase = wr * 64 + m * 16 + (lane >> 4) * 4;
#pragma unroll
      for (int j = 0; j < 4; ++j) {
        int rloc = rbase + j;
        if (rloc < rows) {
          float v = acc[m][n][j] + bias;
          // exactly 2 atomic adds per output element; fp32 add commutes -> deterministic
          unsafeAtomicAdd(&out[(size_t)stok[rloc] * D_DIM + colg], spw[rloc] * v);
        }
      }
    }
  }
}

extern "C" void kernel_launch(void* const* d_in, const int* in_sizes, int n_in,
                              void* d_out, int out_size, void* d_ws, size_t ws_size,
                              hipStream_t stream) {
  (void)in_sizes; (void)n_in; (void)ws_size;
  const float* x     = (const float*)d_in[0];
  const float* noise = (const float*)d_in[1];
  const float* Wg    = (const float*)d_in[2];
  const float* bg    = (const float*)d_in[3];
  const float* Wn    = (const float*)d_in[4];
  const float* bn    = (const float*)d_in[5];
  const float* W1    = (const float*)d_in[6];
  const float* b1    = (const float*)d_in[7];
  const float* W2    = (const float*)d_in[8];
  const float* b2    = (const float*)d_in[9];
  float* out = (float*)d_out;

  char* ws = (char*)d_ws;
  size_t o = 0;
  auto take = [&](size_t b) { size_t r = o; o += (b + 255) & ~(size_t)255; return r; };
  int*   counts     = (int*)(ws + take(16 * 4));        // counts[8], zeroed
  int*   ntiles     = (int*)(ws + take(4));
  int4*  tiles      = (int4*)(ws + take(MAX_TILES * 16));
  int*   tok_e      = (int*)(ws + take((size_t)TP * 4));
  float* tok_w      = (float*)(ws + take((size_t)TP * 4));
  float* gp_tok     = (float*)(ws + take((size_t)T_TOK * 8 * 4));
  int*   pair_token = (int*)(ws + take((size_t)TP * 4));
  float* pair_w     = (float*)(ws + take((size_t)TP * 4));
  unsigned short* xb  = (unsigned short*)(ws + take((size_t)T_TOK * D_DIM * 2));
  unsigned short* w1t = (unsigned short*)(ws + take((size_t)E_EXP * H_DIM * D_DIM * 2));
  unsigned short* w2t = (unsigned short*)(ws + take((size_t)E_EXP * H_DIM * D_DIM * 2));
  unsigned short* hbuf = (unsigned short*)(ws + take((size_t)TP * H_DIM * 2));
  // total ws usage ~201 MB

  hipMemsetAsync(d_out, 0, (size_t)out_size * sizeof(float), stream);
  hipMemsetAsync(counts, 0, 16 * 4, stream);

  front_kernel<<<NGATE + NTRW1, 256, 0, stream>>>(
      W1, w1t, x, noise, Wg, bg, Wn, bn, tok_e, tok_w, gp_tok, counts, xb);
  finalize_kernel<<<1, 256, 0, stream>>>(counts, tiles, ntiles, tok_e, tok_w,
                                         pair_token, pair_w, gp_tok, out);
  ffn1_kernel<<<NTRW2 + MAX_TILES * (H_DIM / BN), 256, 0, stream>>>(
      xb, w1t, b1, pair_token, tiles, ntiles, hbuf, W2, w2t);
  ffn2_kernel<<<dim3(MAX_TILES * (D_DIM / BN)), 256, 0, stream>>>(
      hbuf, w2t, b2, pair_token, pair_w, tiles, ntiles, out);
}

// Round 16
// 428.423 us; speedup vs baseline: 1.0298x; 1.0298x over previous
//
#include <hip/hip_runtime.h>
#include <hip/hip_bf16.h>

// Problem constants
#define T_TOK 4096          // B*S tokens
#define D_DIM 1024
#define H_DIM 4096
#define E_EXP 8
#define K_TOP 2
#define TP (T_TOK * K_TOP)  // 8192 (token, expert) pairs
#define BM 128
#define BN 128
#define BKS 32              // K-step (shorts) -- r2/r5-verified
#define MAX_TILES 72

typedef __attribute__((ext_vector_type(8))) short bf16x8;
typedef __attribute__((ext_vector_type(4))) float f32x4;
typedef __attribute__((ext_vector_type(8))) unsigned short u16x8;
typedef __attribute__((ext_vector_type(4))) unsigned short u16x4;

// LDS chunk swizzle for the GEMMs (verified r2..r15: 0 conflicts)
#define SWZ(row, chunk) ((chunk) ^ (((row) >> 1) & 3))

static __device__ __forceinline__ void gload16(const unsigned short* g, unsigned short* l) {
  __builtin_amdgcn_global_load_lds((const __attribute__((address_space(1))) void*)g,
                                   (__attribute__((address_space(3))) void*)l, 16, 0, 0);
}

static __device__ __forceinline__ unsigned short f2bf(float f) {
  unsigned int bits = __float_as_uint(f);
  unsigned int lsb = (bits >> 16) & 1u;
  bits += 0x7fffu + lsb;
  return (unsigned short)(bits >> 16);
}

static __device__ __forceinline__ float gelu_fast(float u) {
  float z = u * (0.79788456080286536f + 0.0356774081f * u * u);
  float t = __expf(-2.f * z);
  return u / (1.f + t);
}

// ---------------- r8-verified 64x64 transpose body (fp32 LDS [64][65], 16.6KB) ----------------
static __device__ __forceinline__ void transpose64_body(
    const float* __restrict__ s, unsigned short* __restrict__ d, int R, int C,
    int c0, int r0, float* tile, int tid) {           // tile: 64*65 floats
  const int rr = tid >> 4, c4 = tid & 15;
#pragma unroll
  for (int p = 0; p < 4; ++p) {
    int r = rr + p * 16;
    float4 v = *(const float4*)(&s[(size_t)(r0 + r) * C + c0 + c4 * 4]);
    tile[r * 65 + c4 * 4 + 0] = v.x;
    tile[r * 65 + c4 * 4 + 1] = v.y;
    tile[r * 65 + c4 * 4 + 2] = v.z;
    tile[r * 65 + c4 * 4 + 3] = v.w;
  }
  __syncthreads();
  const int cc = tid >> 3, r8 = tid & 7;
#pragma unroll
  for (int p = 0; p < 2; ++p) {
    int c = cc + p * 32;
    u16x8 o;
#pragma unroll
    for (int q = 0; q < 8; ++q) o[q] = f2bf(tile[(r8 * 8 + q) * 65 + c]);
    *(u16x8*)(&d[(size_t)(c0 + c) * R + r0 + r8 * 8]) = o;
  }
}

// =====================================================================
// FRONT: fused {gating (blocks 0..1023)} + {W1 transpose, 64x64 tiles}.
// LDS = 16.9KB (not 33KB!) so gating blocks keep 54% occupancy (r15 lesson).
// W2 transpose lives in ffn1's grid (overlaps the GEMM's idle memory pipe).
// =====================================================================
#define NGATE (T_TOK / 4)                             // 1024
#define NTRW1 ((H_DIM / 64) * (D_DIM / 64) * E_EXP)   // 64*16*8 = 8192
#define NTRW2 ((D_DIM / 64) * (H_DIM / 64) * E_EXP)   // 16*64*8 = 8192

__global__ __launch_bounds__(256) void front_kernel(
    const float* __restrict__ W1, unsigned short* __restrict__ w1t,
    const float* __restrict__ x, const float* __restrict__ noise,
    const float* __restrict__ Wg, const float* __restrict__ bg,
    const float* __restrict__ Wn, const float* __restrict__ bn,
    int* __restrict__ tok_e, float* __restrict__ tok_w,
    float* __restrict__ gp_tok, int* __restrict__ counts,
    unsigned short* __restrict__ xb) {
  __shared__ float tile[64 * 65];              // 16.6KB, transpose blocks only
  int bid = blockIdx.x;
  const int tid = threadIdx.x;

  if (bid < NGATE) {
    // ---------------- gating body (r9/r10/r14-verified) ----------------
    const int lane = tid & 63, wid = tid >> 6;
    const int t = bid * 4 + wid;
    const float* xrow = x + (size_t)t * D_DIM;
    float ag[8] = {0, 0, 0, 0, 0, 0, 0, 0};
    float an[8] = {0, 0, 0, 0, 0, 0, 0, 0};
#pragma unroll 4
    for (int i = 0; i < 16; ++i) {
      int dd = i * 64 + lane;
      float xv = xrow[dd];
      xb[(size_t)t * D_DIM + dd] = f2bf(xv);        // fused x -> bf16
      const float4* g4 = (const float4*)(Wg + (size_t)dd * 8);
      const float4* n4 = (const float4*)(Wn + (size_t)dd * 8);
      float4 ga = g4[0], gb = g4[1], na = n4[0], nb = n4[1];
      ag[0] += xv * ga.x; ag[1] += xv * ga.y; ag[2] += xv * ga.z; ag[3] += xv * ga.w;
      ag[4] += xv * gb.x; ag[5] += xv * gb.y; ag[6] += xv * gb.z; ag[7] += xv * gb.w;
      an[0] += xv * na.x; an[1] += xv * na.y; an[2] += xv * na.z; an[3] += xv * na.w;
      an[4] += xv * nb.x; an[5] += xv * nb.y; an[6] += xv * nb.z; an[7] += xv * nb.w;
    }
#pragma unroll
    for (int e = 0; e < 8; ++e) {
      for (int off = 32; off > 0; off >>= 1) {
        ag[e] += __shfl_down(ag[e], off);
        an[e] += __shfl_down(an[e], off);
      }
    }
    if (lane == 0) {
      float logit[8], noisy[8];
#pragma unroll
      for (int e = 0; e < 8; ++e) {
        logit[e] = ag[e] + bg[e];
        float pre = an[e] + bn[e];
        float sp = fmaxf(pre, 0.f) + log1pf(expf(-fabsf(pre)));   // softplus, stable
        noisy[e] = logit[e] + noise[(size_t)t * 8 + e] * sp;
      }
      float mx = logit[0];
#pragma unroll
      for (int e = 1; e < 8; ++e) mx = fmaxf(mx, logit[e]);
      float s = 0.f, p[8];
#pragma unroll
      for (int e = 0; e < 8; ++e) { p[e] = expf(logit[e] - mx); s += p[e]; }
      float inv = 1.f / s;
#pragma unroll
      for (int e = 0; e < 8; ++e) gp_tok[(size_t)t * 8 + e] = p[e] * inv;
      // top-2 (strict > keeps lowest index on ties, matching lax.top_k)
      int i0 = 0; float v0 = noisy[0];
#pragma unroll
      for (int e = 1; e < 8; ++e) if (noisy[e] > v0) { v0 = noisy[e]; i0 = e; }
      int i1 = -1; float v1 = 0.f;
#pragma unroll
      for (int e = 0; e < 8; ++e) {
        if (e == i0) continue;
        if (i1 < 0 || noisy[e] > v1) { v1 = noisy[e]; i1 = e; }
      }
      float e1 = expf(v1 - v0);      // v0 >= v1
      float w0 = 1.f / (1.f + e1);
      float w1 = e1 * w0;
      tok_e[t * 2 + 0] = i0; tok_e[t * 2 + 1] = i1;
      tok_w[t * 2 + 0] = w0; tok_w[t * 2 + 1] = w1;
      atomicAdd(&counts[i0], 1);
      atomicAdd(&counts[i1], 1);
    }
    return;
  }
  bid -= NGATE;
  // ---------------- W1 transpose: [E][D][H] fp32 -> [E][H][D] bf16 (r14 mapping) ----------------
  const int bx = bid & 63, by = (bid >> 6) & 15, e = bid >> 10;  // C/64=64, R/64=16
  transpose64_body(W1 + (size_t)e * D_DIM * H_DIM,
                   w1t + (size_t)e * D_DIM * H_DIM,
                   D_DIM, H_DIM, bx * 64, by * 64, tile, tid);
}

// =====================================================================
// FINALIZE: fused scan + scatter (LDS cursors) + loss (r14-verified).
// =====================================================================
__global__ __launch_bounds__(256) void finalize_kernel(
    const int* __restrict__ counts, int4* __restrict__ tiles,
    int* __restrict__ ntiles,
    const int* __restrict__ tok_e, const float* __restrict__ tok_w,
    int* __restrict__ pair_token, float* __restrict__ pair_w,
    const float* __restrict__ gp_tok, float* __restrict__ out) {
  __shared__ int s_off[E_EXP];
  __shared__ int s_cur[E_EXP];
  __shared__ float red[256];
  const int tid = threadIdx.x;

  if (tid == 0) {
    int off = 0, nt = 0;
    for (int e = 0; e < E_EXP; ++e) {
      s_off[e] = off;
      int c = counts[e];
      for (int r = 0; r < c; r += BM) {
        tiles[nt] = make_int4(e, off + r, min(BM, c - r), 0);
        ++nt;
      }
      off += c;
    }
    *ntiles = nt;
  }
  if (tid < E_EXP) s_cur[tid] = 0;
  __syncthreads();

  for (int t = tid; t < T_TOK; t += 256) {
#pragma unroll
    for (int k = 0; k < 2; ++k) {
      int e = tok_e[t * 2 + k];
      int pos = atomicAdd(&s_cur[e], 1);
      int p = s_off[e] + pos;
      pair_token[p] = t;
      pair_w[p] = tok_w[t * 2 + k];
    }
  }

  float part[8] = {0, 0, 0, 0, 0, 0, 0, 0};
  for (int r = tid; r < T_TOK; r += 256) {
    const float* g = gp_tok + (size_t)r * 8;
#pragma unroll
    for (int e = 0; e < 8; ++e) part[e] += g[e];
  }
  float total[8];
#pragma unroll
  for (int e = 0; e < 8; ++e) {
    red[tid] = part[e];
    __syncthreads();
    for (int s = 128; s > 0; s >>= 1) {
      if (tid < s) red[tid] += red[tid + s];
      __syncthreads();
    }
    if (tid == 0) total[e] = red[0];
    __syncthreads();
  }
  if (tid == 0) {
    float ll = 0.f;
#pragma unroll
    for (int e = 0; e < 8; ++e)
      ll += ((float)counts[e] / (float)TP) * (total[e] / (float)T_TOK);
    out[(size_t)T_TOK * D_DIM] = ll * (float)E_EXP;
  }
}

// ---------------- FFN1 (+ fused W2 transpose blocks, 64x64 body) ----------------
// GEMM body r6/r8/r10/r14-verified; blocks [0, NTRW2) transpose W2 (BW-bound,
// soaks the GEMM's idle memory pipe); w2t consumed by ffn2 (stream-ordered).
__global__ __launch_bounds__(256) void ffn1_kernel(
    const unsigned short* __restrict__ xb,    // [T][D] bf16
    const unsigned short* __restrict__ w1t,   // [E][H][D] bf16 (transposed)
    const float* __restrict__ b1,             // [E][H]
    const int* __restrict__ pair_token,       // [TP]
    const int4* __restrict__ tiles, const int* __restrict__ ntiles,
    unsigned short* __restrict__ hbuf,        // [TP][H] bf16
    const float* __restrict__ W2, unsigned short* __restrict__ w2t) {
  __shared__ unsigned short sh[16384];        // 32KB; transpose reuses as float[64*65]
  const int tid = threadIdx.x;
  int bid = blockIdx.x;

  if (bid < NTRW2) {
    // W2 transpose: [E][H][D] fp32 -> [E][D][H] bf16 (r14 mapping mirrored)
    const int bx = bid & 15, by = (bid >> 4) & 63, e = bid >> 10;  // C/64=16, R/64=64
    transpose64_body(W2 + (size_t)e * D_DIM * H_DIM,
                     w2t + (size_t)e * D_DIM * H_DIM,
                     H_DIM, D_DIM, bx * 64, by * 64, (float*)sh, tid);
    return;
  }
  bid -= NTRW2;

  const int NB = H_DIM / BN;                  // 32
  const int nwg = MAX_TILES * NB;             // 2304, %8==0
  int wg = (bid & 7) * (nwg >> 3) + (bid >> 3);   // bijective XCD chunking
  int tileId = wg / NB, nb = wg - tileId * NB;
  if (tileId >= *ntiles) return;
  int4 tl = tiles[tileId];
  const int e = tl.x, row0 = tl.y, rows = tl.z;
  const int n0 = nb * BN;

#define AS1(buf) (sh + (buf) * 4096)
#define BS1(buf) (sh + 8192 + (buf) * 4096)

  const int wid = tid >> 6, lane = tid & 63;
  const int sr = tid >> 2;
  const int sc = tid & 3;
  const int scz = SWZ(sr, sc) * 8;

  int r0a = row0 + sr;       if (r0a > TP - 1) r0a = TP - 1;
  int r1a = row0 + sr + 64;  if (r1a > TP - 1) r1a = TP - 1;
  const unsigned short* a0 = xb + (size_t)pair_token[r0a] * D_DIM + scz;
  const unsigned short* a1 = xb + (size_t)pair_token[r1a] * D_DIM + scz;
  const unsigned short* bp0 = w1t + ((size_t)e * H_DIM + (n0 + sr)) * D_DIM + scz;
  const unsigned short* bp1 = w1t + ((size_t)e * H_DIM + (n0 + sr + 64)) * D_DIM + scz;

  const int wbase = wid * 512;
  const int wr = wid >> 1, wc = wid & 1;
  const int lrow = lane & 15, lkc = lane >> 4;

  f32x4 acc[4][4] = {};

  auto stage = [&](int buf, int k0) {
    gload16(a0 + k0, AS1(buf) + wbase);
    gload16(a1 + k0, AS1(buf) + wbase + 2048);
    gload16(bp0 + k0, BS1(buf) + wbase);
    gload16(bp1 + k0, BS1(buf) + wbase + 2048);
  };
  auto compute_step = [&](int buf) {
    bf16x8 af[4], bfr[4];
#pragma unroll
    for (int m = 0; m < 4; ++m) {
      int r = wr * 64 + m * 16 + lrow;
      af[m] = *(const bf16x8*)(AS1(buf) + r * BKS + SWZ(r, lkc) * 8);
    }
#pragma unroll
    for (int n = 0; n < 4; ++n) {
      int r = wc * 64 + n * 16 + lrow;
      bfr[n] = *(const bf16x8*)(BS1(buf) + r * BKS + SWZ(r, lkc) * 8);
    }
#pragma unroll
    for (int m = 0; m < 4; ++m)
#pragma unroll
      for (int n = 0; n < 4; ++n)
        acc[m][n] = __builtin_amdgcn_mfma_f32_16x16x32_bf16(af[m], bfr[n], acc[m][n], 0, 0, 0);
  };

  const int NK = D_DIM / BKS;                 // 32
  stage(0, 0);
  stage(1, BKS);
  int cur = 0;
  for (int k = 0; k < NK - 1; ++k) {
    asm volatile("s_waitcnt vmcnt(4)" ::: "memory");
    __builtin_amdgcn_s_barrier();
    __builtin_amdgcn_sched_barrier(0);
    compute_step(cur);
    __builtin_amdgcn_sched_barrier(0);
    __builtin_amdgcn_s_barrier();
    if (k < NK - 2) stage(cur, (k + 2) * BKS);
    cur ^= 1;
  }
  asm volatile("s_waitcnt vmcnt(0)" ::: "memory");
  __builtin_amdgcn_s_barrier();
  __builtin_amdgcn_sched_barrier(0);
  compute_step(cur);

  // epilogue: gelu -> LDS [128][128] (chunk-XOR swizzled) -> coalesced stores
  __syncthreads();
#pragma unroll
  for (int n = 0; n < 4; ++n) {
    int clocal = wc * 64 + n * 16 + lrow;
    float bias = b1[(size_t)e * H_DIM + n0 + clocal];
    int chunk = clocal >> 3, within = clocal & 7;
#pragma unroll
    for (int m = 0; m < 4; ++m) {
#pragma unroll
      for (int j = 0; j < 4; ++j) {
        int rloc = wr * 64 + m * 16 + (lane >> 4) * 4 + j;
        float v = acc[m][n][j] + bias;
        sh[rloc * 128 + ((chunk ^ ((rloc >> 1) & 7)) * 8) + within] = f2bf(gelu_fast(v));
      }
    }
  }
  __syncthreads();
#pragma unroll
  for (int it = 0; it < 8; ++it) {
    int u = tid + 256 * it;
    int r = u >> 4, cg = u & 15;
    if (r < rows) {
      u16x8 v = *(const u16x8*)(&sh[r * 128 + ((cg ^ ((r >> 1) & 7)) * 8)]);
      *(u16x8*)(&hbuf[(size_t)(row0 + r) * H_DIM + n0 + cg * 8]) = v;
    }
  }
#undef AS1
#undef BS1
}

// ---------------- FFN2 (r8/r10/r14-verified) ----------------
__global__ __launch_bounds__(256) void ffn2_kernel(
    const unsigned short* __restrict__ hbuf,  // [TP][H] bf16
    const unsigned short* __restrict__ w2t,   // [E][D][H] bf16 (transposed)
    const float* __restrict__ b2,             // [E][D]
    const int* __restrict__ pair_token, const float* __restrict__ pair_w,
    const int4* __restrict__ tiles, const int* __restrict__ ntiles,
    float* __restrict__ out) {
  const int NB = D_DIM / BN;                  // 8
  const int nwg = MAX_TILES * NB;             // 576, %8==0
  int bid = blockIdx.x;
  int wg = (bid & 7) * (nwg >> 3) + (bid >> 3);
  int tileId = wg / NB, nb = wg - tileId * NB;
  if (tileId >= *ntiles) return;
  int4 tl = tiles[tileId];
  const int e = tl.x, row0 = tl.y, rows = tl.z;
  const int n0 = nb * BN;

  __shared__ unsigned short As[2][BM * BKS];
  __shared__ unsigned short Bs[2][BN * BKS];
  __shared__ int stok[BM];
  __shared__ float spw[BM];

  const int tid = threadIdx.x;
  if (tid < BM) {
    int rr = row0 + tid; if (rr > TP - 1) rr = TP - 1;
    stok[tid] = pair_token[rr];
    spw[tid] = pair_w[rr];
  }

  const int wid = tid >> 6, lane = tid & 63;
  const int sr = tid >> 2;
  const int sc = tid & 3;
  const int scz = SWZ(sr, sc) * 8;

  int r0a = row0 + sr;       if (r0a > TP - 1) r0a = TP - 1;
  int r1a = row0 + sr + 64;  if (r1a > TP - 1) r1a = TP - 1;
  const unsigned short* a0 = hbuf + (size_t)r0a * H_DIM + scz;
  const unsigned short* a1 = hbuf + (size_t)r1a * H_DIM + scz;
  const unsigned short* bp0 = w2t + ((size_t)e * D_DIM + (n0 + sr)) * H_DIM + scz;
  const unsigned short* bp1 = w2t + ((size_t)e * D_DIM + (n0 + sr + 64)) * H_DIM + scz;

  const int wbase = wid * 512;
  const int wr = wid >> 1, wc = wid & 1;
  const int lrow = lane & 15, lkc = lane >> 4;

  f32x4 acc[4][4] = {};

  auto stage = [&](int buf, int k0) {
    gload16(a0 + k0, &As[buf][wbase]);
    gload16(a1 + k0, &As[buf][wbase + 2048]);
    gload16(bp0 + k0, &Bs[buf][wbase]);
    gload16(bp1 + k0, &Bs[buf][wbase + 2048]);
  };
  auto compute_step = [&](int buf) {
    bf16x8 af[4], bfr[4];
#pragma unroll
    for (int m = 0; m < 4; ++m) {
      int r = wr * 64 + m * 16 + lrow;
      af[m] = *(const bf16x8*)(&As[buf][r * BKS + SWZ(r, lkc) * 8]);
    }
#pragma unroll
    for (int n = 0; n < 4; ++n) {
      int r = wc * 64 + n * 16 + lrow;
      bfr[n] = *(const bf16x8*)(&Bs[buf][r * BKS + SWZ(r, lkc) * 8]);
    }
#pragma unroll
    for (int m = 0; m < 4; ++m)
#pragma unroll
      for (int n = 0; n < 4; ++n)
        acc[m][n] = __builtin_amdgcn_mfma_f32_16x16x32_bf16(af[m], bfr[n], acc[m][n], 0, 0, 0);
  };

  const int NK = H_DIM / BKS;                 // 128
  stage(0, 0);
  stage(1, BKS);
  int cur = 0;
  for (int k = 0; k < NK - 1; ++k) {
    asm volatile("s_waitcnt vmcnt(4)" ::: "memory");
    __builtin_amdgcn_s_barrier();
    __builtin_amdgcn_sched_barrier(0);
    compute_step(cur);
    __builtin_amdgcn_sched_barrier(0);
    __builtin_amdgcn_s_barrier();
    if (k < NK - 2) stage(cur, (k + 2) * BKS);
    cur ^= 1;
  }
  asm volatile("s_waitcnt vmcnt(0)" ::: "memory");
  __builtin_amdgcn_s_barrier();
  __builtin_amdgcn_sched_barrier(0);
  compute_step(cur);

  const int colbase = n0 + wc * 64;
#pragma unroll
  for (int n = 0; n < 4; ++n) {
    int colg = colbase + n * 16 + lrow;
    float bias = b2[(size_t)e * D_DIM + colg];
#pragma unroll
    for (int m = 0; m < 4; ++m) {
      int rbase = wr * 64 + m * 16 + (lane >> 4) * 4;
#pragma unroll
      for (int j = 0; j < 4; ++j) {
        int rloc = rbase + j;
        if (rloc < rows) {
          float v = acc[m][n][j] + bias;
          // exactly 2 atomic adds per output element; fp32 add commutes -> deterministic
          unsafeAtomicAdd(&out[(size_t)stok[rloc] * D_DIM + colg], spw[rloc] * v);
        }
      }
    }
  }
}

extern "C" void kernel_launch(void* const* d_in, const int* in_sizes, int n_in,
                              void* d_out, int out_size, void* d_ws, size_t ws_size,
                              hipStream_t stream) {
  (void)in_sizes; (void)n_in; (void)ws_size;
  const float* x     = (const float*)d_in[0];
  const float* noise = (const float*)d_in[1];
  const float* Wg    = (const float*)d_in[2];
  const float* bg    = (const float*)d_in[3];
  const float* Wn    = (const float*)d_in[4];
  const float* bn    = (const float*)d_in[5];
  const float* W1    = (const float*)d_in[6];
  const float* b1    = (const float*)d_in[7];
  const float* W2    = (const float*)d_in[8];
  const float* b2    = (const float*)d_in[9];
  float* out = (float*)d_out;

  char* ws = (char*)d_ws;
  size_t o = 0;
  auto take = [&](size_t b) { size_t r = o; o += (b + 255) & ~(size_t)255; return r; };
  int*   counts     = (int*)(ws + take(16 * 4));        // counts[8], zeroed
  int*   ntiles     = (int*)(ws + take(4));
  int4*  tiles      = (int4*)(ws + take(MAX_TILES * 16));
  int*   tok_e      = (int*)(ws + take((size_t)TP * 4));
  float* tok_w      = (float*)(ws + take((size_t)TP * 4));
  float* gp_tok     = (float*)(ws + take((size_t)T_TOK * 8 * 4));
  int*   pair_token = (int*)(ws + take((size_t)TP * 4));
  float* pair_w     = (float*)(ws + take((size_t)TP * 4));
  unsigned short* xb  = (unsigned short*)(ws + take((size_t)T_TOK * D_DIM * 2));
  unsigned short* w1t = (unsigned short*)(ws + take((size_t)E_EXP * H_DIM * D_DIM * 2));
  unsigned short* w2t = (unsigned short*)(ws + take((size_t)E_EXP * H_DIM * D_DIM * 2));
  unsigned short* hbuf = (unsigned short*)(ws + take((size_t)TP * H_DIM * 2));
  // total ws usage ~201 MB

  hipMemsetAsync(d_out, 0, (size_t)out_size * sizeof(float), stream);
  hipMemsetAsync(counts, 0, 16 * 4, stream);

  front_kernel<<<NGATE + NTRW1, 256, 0, stream>>>(
      W1, w1t, x, noise, Wg, bg, Wn, bn, tok_e, tok_w, gp_tok, counts, xb);
  finalize_kernel<<<1, 256, 0, stream>>>(counts, tiles, ntiles, tok_e, tok_w,
                                         pair_token, pair_w, gp_tok, out);
  ffn1_kernel<<<NTRW2 + MAX_TILES * (H_DIM / BN), 256, 0, stream>>>(
      xb, w1t, b1, pair_token, tiles, ntiles, hbuf, W2, w2t);
  ffn2_kernel<<<dim3(MAX_TILES * (D_DIM / BN)), 256, 0, stream>>>(
      hbuf, w2t, b2, pair_token, pair_w, tiles, ntiles, out);
}

// Round 17
// 426.129 us; speedup vs baseline: 1.0353x; 1.0054x over previous
//
#include <hip/hip_runtime.h>
#include <hip/hip_bf16.h>

// Problem constants
#define T_TOK 4096          // B*S tokens
#define D_DIM 1024
#define H_DIM 4096
#define E_EXP 8
#define K_TOP 2
#define TP (T_TOK * K_TOP)  // 8192 (token, expert) pairs
#define BM 128
#define BN 128
#define BKS 32              // K-step (shorts) -- r2/r5-verified
#define MAX_TILES 72

typedef __attribute__((ext_vector_type(8))) short bf16x8;
typedef __attribute__((ext_vector_type(4))) float f32x4;
typedef __attribute__((ext_vector_type(8))) unsigned short u16x8;
typedef __attribute__((ext_vector_type(4))) unsigned short u16x4;

// LDS chunk swizzle for the GEMMs (verified r2..r16: 0 conflicts)
#define SWZ(row, chunk) ((chunk) ^ (((row) >> 1) & 3))

static __device__ __forceinline__ void gload16(const unsigned short* g, unsigned short* l) {
  __builtin_amdgcn_global_load_lds((const __attribute__((address_space(1))) void*)g,
                                   (__attribute__((address_space(3))) void*)l, 16, 0, 0);
}

static __device__ __forceinline__ unsigned short f2bf(float f) {
  unsigned int bits = __float_as_uint(f);
  unsigned int lsb = (bits >> 16) & 1u;
  bits += 0x7fffu + lsb;
  return (unsigned short)(bits >> 16);
}

static __device__ __forceinline__ float gelu_fast(float u) {
  float z = u * (0.79788456080286536f + 0.0356774081f * u * u);
  float t = __expf(-2.f * z);
  return u / (1.f + t);
}

// ---------------- r8-verified 64x64 transpose body (fp32 LDS [64][65], 16.6KB) ----------------
static __device__ __forceinline__ void transpose64_body(
    const float* __restrict__ s, unsigned short* __restrict__ d, int R, int C,
    int c0, int r0, float* tile, int tid) {           // tile: 64*65 floats
  const int rr = tid >> 4, c4 = tid & 15;
#pragma unroll
  for (int p = 0; p < 4; ++p) {
    int r = rr + p * 16;
    float4 v = *(const float4*)(&s[(size_t)(r0 + r) * C + c0 + c4 * 4]);
    tile[r * 65 + c4 * 4 + 0] = v.x;
    tile[r * 65 + c4 * 4 + 1] = v.y;
    tile[r * 65 + c4 * 4 + 2] = v.z;
    tile[r * 65 + c4 * 4 + 3] = v.w;
  }
  __syncthreads();
  const int cc = tid >> 3, r8 = tid & 7;
#pragma unroll
  for (int p = 0; p < 2; ++p) {
    int c = cc + p * 32;
    u16x8 o;
#pragma unroll
    for (int q = 0; q < 8; ++q) o[q] = f2bf(tile[(r8 * 8 + q) * 65 + c]);
    *(u16x8*)(&d[(size_t)(c0 + c) * R + r0 + r8 * 8]) = o;
  }
}

// =====================================================================
// FRONT: fused {gating} + {W1 transpose 64x64} + {d_out zeroing blocks}.
// LDS = 16.6KB so gating keeps its 54% occupancy (r15/r16 lesson).
// W2 transpose lives in ffn1's grid (overlaps the GEMM's idle memory pipe).
// =====================================================================
#define NGATE (T_TOK / 4)                             // 1024
#define NTRW1 ((H_DIM / 64) * (D_DIM / 64) * E_EXP)   // 64*16*8 = 8192
#define NTRW2 ((D_DIM / 64) * (H_DIM / 64) * E_EXP)   // 16*64*8 = 8192
#define NZERO (T_TOK * D_DIM / 4096)                  // 1024 blocks x 16KB

__global__ __launch_bounds__(256) void front_kernel(
    const float* __restrict__ W1, unsigned short* __restrict__ w1t,
    const float* __restrict__ x, const float* __restrict__ noise,
    const float* __restrict__ Wg, const float* __restrict__ bg,
    const float* __restrict__ Wn, const float* __restrict__ bn,
    int* __restrict__ tok_e, float* __restrict__ tok_w,
    float* __restrict__ gp_tok, int* __restrict__ counts,
    unsigned short* __restrict__ xb, float* __restrict__ out) {
  __shared__ float tile[64 * 65];              // 16.6KB, transpose blocks only
  int bid = blockIdx.x;
  const int tid = threadIdx.x;

  if (bid < NGATE) {
    // ---------------- gating body (r9/r10/r14/r16-verified) ----------------
    const int lane = tid & 63, wid = tid >> 6;
    const int t = bid * 4 + wid;
    const float* xrow = x + (size_t)t * D_DIM;
    float ag[8] = {0, 0, 0, 0, 0, 0, 0, 0};
    float an[8] = {0, 0, 0, 0, 0, 0, 0, 0};
#pragma unroll 4
    for (int i = 0; i < 16; ++i) {
      int dd = i * 64 + lane;
      float xv = xrow[dd];
      xb[(size_t)t * D_DIM + dd] = f2bf(xv);        // fused x -> bf16
      const float4* g4 = (const float4*)(Wg + (size_t)dd * 8);
      const float4* n4 = (const float4*)(Wn + (size_t)dd * 8);
      float4 ga = g4[0], gb = g4[1], na = n4[0], nb = n4[1];
      ag[0] += xv * ga.x; ag[1] += xv * ga.y; ag[2] += xv * ga.z; ag[3] += xv * ga.w;
      ag[4] += xv * gb.x; ag[5] += xv * gb.y; ag[6] += xv * gb.z; ag[7] += xv * gb.w;
      an[0] += xv * na.x; an[1] += xv * na.y; an[2] += xv * na.z; an[3] += xv * na.w;
      an[4] += xv * nb.x; an[5] += xv * nb.y; an[6] += xv * nb.z; an[7] += xv * nb.w;
    }
#pragma unroll
    for (int e = 0; e < 8; ++e) {
      for (int off = 32; off > 0; off >>= 1) {
        ag[e] += __shfl_down(ag[e], off);
        an[e] += __shfl_down(an[e], off);
      }
    }
    if (lane == 0) {
      float logit[8], noisy[8];
#pragma unroll
      for (int e = 0; e < 8; ++e) {
        logit[e] = ag[e] + bg[e];
        float pre = an[e] + bn[e];
        float sp = fmaxf(pre, 0.f) + log1pf(expf(-fabsf(pre)));   // softplus, stable
        noisy[e] = logit[e] + noise[(size_t)t * 8 + e] * sp;
      }
      float mx = logit[0];
#pragma unroll
      for (int e = 1; e < 8; ++e) mx = fmaxf(mx, logit[e]);
      float s = 0.f, p[8];
#pragma unroll
      for (int e = 0; e < 8; ++e) { p[e] = expf(logit[e] - mx); s += p[e]; }
      float inv = 1.f / s;
#pragma unroll
      for (int e = 0; e < 8; ++e) gp_tok[(size_t)t * 8 + e] = p[e] * inv;
      // top-2 (strict > keeps lowest index on ties, matching lax.top_k)
      int i0 = 0; float v0 = noisy[0];
#pragma unroll
      for (int e = 1; e < 8; ++e) if (noisy[e] > v0) { v0 = noisy[e]; i0 = e; }
      int i1 = -1; float v1 = 0.f;
#pragma unroll
      for (int e = 0; e < 8; ++e) {
        if (e == i0) continue;
        if (i1 < 0 || noisy[e] > v1) { v1 = noisy[e]; i1 = e; }
      }
      float e1 = expf(v1 - v0);      // v0 >= v1
      float w0 = 1.f / (1.f + e1);
      float w1 = e1 * w0;
      tok_e[t * 2 + 0] = i0; tok_e[t * 2 + 1] = i1;
      tok_w[t * 2 + 0] = w0; tok_w[t * 2 + 1] = w1;
      atomicAdd(&counts[i0], 1);
      atomicAdd(&counts[i1], 1);
    }
    return;
  }
  bid -= NGATE;
  if (bid < NTRW1) {
    // ---------------- W1 transpose: [E][D][H] fp32 -> [E][H][D] bf16 ----------------
    const int bx = bid & 63, by = (bid >> 6) & 15, e = bid >> 10;  // C/64=64, R/64=16
    transpose64_body(W1 + (size_t)e * D_DIM * H_DIM,
                     w1t + (size_t)e * D_DIM * H_DIM,
                     D_DIM, H_DIM, bx * 64, by * 64, tile, tid);
    return;
  }
  bid -= NTRW1;
  // ---------------- d_out zeroing (replaces the 16MB hipMemsetAsync dispatch) ----------------
  // out consumed only by finalize (loss write) and ffn2 (atomics), both later
  // in the stream -> order-safe. 4096 floats per block via f32x4 stores.
  {
    f32x4 z = {0.f, 0.f, 0.f, 0.f};
#pragma unroll
    for (int it = 0; it < 4; ++it) {
      size_t idx = (size_t)bid * 4096 + it * 1024 + tid * 4;
      *(f32x4*)(&out[idx]) = z;
    }
    if (bid == 0 && tid == 0) out[(size_t)T_TOK * D_DIM] = 0.f;  // loss slot
  }
}

// =====================================================================
// FINALIZE: fused scan + scatter (LDS cursors) + loss (r14/r16-verified).
// =====================================================================
__global__ __launch_bounds__(256) void finalize_kernel(
    const int* __restrict__ counts, int4* __restrict__ tiles,
    int* __restrict__ ntiles,
    const int* __restrict__ tok_e, const float* __restrict__ tok_w,
    int* __restrict__ pair_token, float* __restrict__ pair_w,
    const float* __restrict__ gp_tok, float* __restrict__ out) {
  __shared__ int s_off[E_EXP];
  __shared__ int s_cur[E_EXP];
  __shared__ float red[256];
  const int tid = threadIdx.x;

  if (tid == 0) {
    int off = 0, nt = 0;
    for (int e = 0; e < E_EXP; ++e) {
      s_off[e] = off;
      int c = counts[e];
      for (int r = 0; r < c; r += BM) {
        tiles[nt] = make_int4(e, off + r, min(BM, c - r), 0);
        ++nt;
      }
      off += c;
    }
    *ntiles = nt;
  }
  if (tid < E_EXP) s_cur[tid] = 0;
  __syncthreads();

  for (int t = tid; t < T_TOK; t += 256) {
#pragma unroll
    for (int k = 0; k < 2; ++k) {
      int e = tok_e[t * 2 + k];
      int pos = atomicAdd(&s_cur[e], 1);
      int p = s_off[e] + pos;
      pair_token[p] = t;
      pair_w[p] = tok_w[t * 2 + k];
    }
  }

  float part[8] = {0, 0, 0, 0, 0, 0, 0, 0};
  for (int r = tid; r < T_TOK; r += 256) {
    const float* g = gp_tok + (size_t)r * 8;
#pragma unroll
    for (int e = 0; e < 8; ++e) part[e] += g[e];
  }
  float total[8];
#pragma unroll
  for (int e = 0; e < 8; ++e) {
    red[tid] = part[e];
    __syncthreads();
    for (int s = 128; s > 0; s >>= 1) {
      if (tid < s) red[tid] += red[tid + s];
      __syncthreads();
    }
    if (tid == 0) total[e] = red[0];
    __syncthreads();
  }
  if (tid == 0) {
    float ll = 0.f;
#pragma unroll
    for (int e = 0; e < 8; ++e)
      ll += ((float)counts[e] / (float)TP) * (total[e] / (float)T_TOK);
    out[(size_t)T_TOK * D_DIM] = ll * (float)E_EXP;
  }
}

// ---------------- FFN1 (+ fused W2 transpose blocks, 64x64 body) ----------------
// GEMM body r6/r8/r10/r16-verified; blocks [0, NTRW2) transpose W2 (BW-bound,
// soaks the GEMM's idle memory pipe); w2t consumed by ffn2 (stream-ordered).
__global__ __launch_bounds__(256) void ffn1_kernel(
    const unsigned short* __restrict__ xb,    // [T][D] bf16
    const unsigned short* __restrict__ w1t,   // [E][H][D] bf16 (transposed)
    const float* __restrict__ b1,             // [E][H]
    const int* __restrict__ pair_token,       // [TP]
    const int4* __restrict__ tiles, const int* __restrict__ ntiles,
    unsigned short* __restrict__ hbuf,        // [TP][H] bf16
    const float* __restrict__ W2, unsigned short* __restrict__ w2t) {
  __shared__ unsigned short sh[16384];        // 32KB; transpose reuses as float[64*65]
  const int tid = threadIdx.x;
  int bid = blockIdx.x;

  if (bid < NTRW2) {
    // W2 transpose: [E][H][D] fp32 -> [E][D][H] bf16
    const int bx = bid & 15, by = (bid >> 4) & 63, e = bid >> 10;  // C/64=16, R/64=64
    transpose64_body(W2 + (size_t)e * D_DIM * H_DIM,
                     w2t + (size_t)e * D_DIM * H_DIM,
                     H_DIM, D_DIM, bx * 64, by * 64, (float*)sh, tid);
    return;
  }
  bid -= NTRW2;

  const int NB = H_DIM / BN;                  // 32
  const int nwg = MAX_TILES * NB;             // 2304, %8==0
  int wg = (bid & 7) * (nwg >> 3) + (bid >> 3);   // bijective XCD chunking
  int tileId = wg / NB, nb = wg - tileId * NB;
  if (tileId >= *ntiles) return;
  int4 tl = tiles[tileId];
  const int e = tl.x, row0 = tl.y, rows = tl.z;
  const int n0 = nb * BN;

#define AS1(buf) (sh + (buf) * 4096)
#define BS1(buf) (sh + 8192 + (buf) * 4096)

  const int wid = tid >> 6, lane = tid & 63;
  const int sr = tid >> 2;
  const int sc = tid & 3;
  const int scz = SWZ(sr, sc) * 8;

  int r0a = row0 + sr;       if (r0a > TP - 1) r0a = TP - 1;
  int r1a = row0 + sr + 64;  if (r1a > TP - 1) r1a = TP - 1;
  const unsigned short* a0 = xb + (size_t)pair_token[r0a] * D_DIM + scz;
  const unsigned short* a1 = xb + (size_t)pair_token[r1a] * D_DIM + scz;
  const unsigned short* bp0 = w1t + ((size_t)e * H_DIM + (n0 + sr)) * D_DIM + scz;
  const unsigned short* bp1 = w1t + ((size_t)e * H_DIM + (n0 + sr + 64)) * D_DIM + scz;

  const int wbase = wid * 512;
  const int wr = wid >> 1, wc = wid & 1;
  const int lrow = lane & 15, lkc = lane >> 4;

  f32x4 acc[4][4] = {};

  auto stage = [&](int buf, int k0) {
    gload16(a0 + k0, AS1(buf) + wbase);
    gload16(a1 + k0, AS1(buf) + wbase + 2048);
    gload16(bp0 + k0, BS1(buf) + wbase);
    gload16(bp1 + k0, BS1(buf) + wbase + 2048);
  };
  auto compute_step = [&](int buf) {
    bf16x8 af[4], bfr[4];
#pragma unroll
    for (int m = 0; m < 4; ++m) {
      int r = wr * 64 + m * 16 + lrow;
      af[m] = *(const bf16x8*)(AS1(buf) + r * BKS + SWZ(r, lkc) * 8);
    }
#pragma unroll
    for (int n = 0; n < 4; ++n) {
      int r = wc * 64 + n * 16 + lrow;
      bfr[n] = *(const bf16x8*)(BS1(buf) + r * BKS + SWZ(r, lkc) * 8);
    }
#pragma unroll
    for (int m = 0; m < 4; ++m)
#pragma unroll
      for (int n = 0; n < 4; ++n)
        acc[m][n] = __builtin_amdgcn_mfma_f32_16x16x32_bf16(af[m], bfr[n], acc[m][n], 0, 0, 0);
  };

  const int NK = D_DIM / BKS;                 // 32
  stage(0, 0);
  stage(1, BKS);
  int cur = 0;
  for (int k = 0; k < NK - 1; ++k) {
    asm volatile("s_waitcnt vmcnt(4)" ::: "memory");
    __builtin_amdgcn_s_barrier();
    __builtin_amdgcn_sched_barrier(0);
    compute_step(cur);
    __builtin_amdgcn_sched_barrier(0);
    __builtin_amdgcn_s_barrier();
    if (k < NK - 2) stage(cur, (k + 2) * BKS);
    cur ^= 1;
  }
  asm volatile("s_waitcnt vmcnt(0)" ::: "memory");
  __builtin_amdgcn_s_barrier();
  __builtin_amdgcn_sched_barrier(0);
  compute_step(cur);

  // epilogue: gelu -> LDS [128][128] (chunk-XOR swizzled) -> coalesced stores
  __syncthreads();
#pragma unroll
  for (int n = 0; n < 4; ++n) {
    int clocal = wc * 64 + n * 16 + lrow;
    float bias = b1[(size_t)e * H_DIM + n0 + clocal];
    int chunk = clocal >> 3, within = clocal & 7;
#pragma unroll
    for (int m = 0; m < 4; ++m) {
#pragma unroll
      for (int j = 0; j < 4; ++j) {
        int rloc = wr * 64 + m * 16 + (lane >> 4) * 4 + j;
        float v = acc[m][n][j] + bias;
        sh[rloc * 128 + ((chunk ^ ((rloc >> 1) & 7)) * 8) + within] = f2bf(gelu_fast(v));
      }
    }
  }
  __syncthreads();
#pragma unroll
  for (int it = 0; it < 8; ++it) {
    int u = tid + 256 * it;
    int r = u >> 4, cg = u & 15;
    if (r < rows) {
      u16x8 v = *(const u16x8*)(&sh[r * 128 + ((cg ^ ((r >> 1) & 7)) * 8)]);
      *(u16x8*)(&hbuf[(size_t)(row0 + r) * H_DIM + n0 + cg * 8]) = v;
    }
  }
#undef AS1
#undef BS1
}

// ---------------- FFN2 (r8/r10/r14/r16-verified) ----------------
__global__ __launch_bounds__(256) void ffn2_kernel(
    const unsigned short* __restrict__ hbuf,  // [TP][H] bf16
    const unsigned short* __restrict__ w2t,   // [E][D][H] bf16 (transposed)
    const float* __restrict__ b2,             // [E][D]
    const int* __restrict__ pair_token, const float* __restrict__ pair_w,
    const int4* __restrict__ tiles, const int* __restrict__ ntiles,
    float* __restrict__ out) {
  const int NB = D_DIM / BN;                  // 8
  const int nwg = MAX_TILES * NB;             // 576, %8==0
  int bid = blockIdx.x;
  int wg = (bid & 7) * (nwg >> 3) + (bid >> 3);
  int tileId = wg / NB, nb = wg - tileId * NB;
  if (tileId >= *ntiles) return;
  int4 tl = tiles[tileId];
  const int e = tl.x, row0 = tl.y, rows = tl.z;
  const int n0 = nb * BN;

  __shared__ unsigned short As[2][BM * BKS];
  __shared__ unsigned short Bs[2][BN * BKS];
  __shared__ int stok[BM];
  __shared__ float spw[BM];

  const int tid = threadIdx.x;
  if (tid < BM) {
    int rr = row0 + tid; if (rr > TP - 1) rr = TP - 1;
    stok[tid] = pair_token[rr];
    spw[tid] = pair_w[rr];
  }

  const int wid = tid >> 6, lane = tid & 63;
  const int sr = tid >> 2;
  const int sc = tid & 3;
  const int scz = SWZ(sr, sc) * 8;

  int r0a = row0 + sr;       if (r0a > TP - 1) r0a = TP - 1;
  int r1a = row0 + sr + 64;  if (r1a > TP - 1) r1a = TP - 1;
  const unsigned short* a0 = hbuf + (size_t)r0a * H_DIM + scz;
  const unsigned short* a1 = hbuf + (size_t)r1a * H_DIM + scz;
  const unsigned short* bp0 = w2t + ((size_t)e * D_DIM + (n0 + sr)) * H_DIM + scz;
  const unsigned short* bp1 = w2t + ((size_t)e * D_DIM + (n0 + sr + 64)) * H_DIM + scz;

  const int wbase = wid * 512;
  const int wr = wid >> 1, wc = wid & 1;
  const int lrow = lane & 15, lkc = lane >> 4;

  f32x4 acc[4][4] = {};

  auto stage = [&](int buf, int k0) {
    gload16(a0 + k0, &As[buf][wbase]);
    gload16(a1 + k0, &As[buf][wbase + 2048]);
    gload16(bp0 + k0, &Bs[buf][wbase]);
    gload16(bp1 + k0, &Bs[buf][wbase + 2048]);
  };
  auto compute_step = [&](int buf) {
    bf16x8 af[4], bfr[4];
#pragma unroll
    for (int m = 0; m < 4; ++m) {
      int r = wr * 64 + m * 16 + lrow;
      af[m] = *(const bf16x8*)(&As[buf][r * BKS + SWZ(r, lkc) * 8]);
    }
#pragma unroll
    for (int n = 0; n < 4; ++n) {
      int r = wc * 64 + n * 16 + lrow;
      bfr[n] = *(const bf16x8*)(&Bs[buf][r * BKS + SWZ(r, lkc) * 8]);
    }
#pragma unroll
    for (int m = 0; m < 4; ++m)
#pragma unroll
      for (int n = 0; n < 4; ++n)
        acc[m][n] = __builtin_amdgcn_mfma_f32_16x16x32_bf16(af[m], bfr[n], acc[m][n], 0, 0, 0);
  };

  const int NK = H_DIM / BKS;                 // 128
  stage(0, 0);
  stage(1, BKS);
  int cur = 0;
  for (int k = 0; k < NK - 1; ++k) {
    asm volatile("s_waitcnt vmcnt(4)" ::: "memory");
    __builtin_amdgcn_s_barrier();
    __builtin_amdgcn_sched_barrier(0);
    compute_step(cur);
    __builtin_amdgcn_sched_barrier(0);
    __builtin_amdgcn_s_barrier();
    if (k < NK - 2) stage(cur, (k + 2) * BKS);
    cur ^= 1;
  }
  asm volatile("s_waitcnt vmcnt(0)" ::: "memory");
  __builtin_amdgcn_s_barrier();
  __builtin_amdgcn_sched_barrier(0);
  compute_step(cur);

  const int colbase = n0 + wc * 64;
#pragma unroll
  for (int n = 0; n < 4; ++n) {
    int colg = colbase + n * 16 + lrow;
    float bias = b2[(size_t)e * D_DIM + colg];
#pragma unroll
    for (int m = 0; m < 4; ++m) {
      int rbase = wr * 64 + m * 16 + (lane >> 4) * 4;
#pragma unroll
      for (int j = 0; j < 4; ++j) {
        int rloc = rbase + j;
        if (rloc < rows) {
          float v = acc[m][n][j] + bias;
          // exactly 2 atomic adds per output element; fp32 add commutes -> deterministic
          unsafeAtomicAdd(&out[(size_t)stok[rloc] * D_DIM + colg], spw[rloc] * v);
        }
      }
    }
  }
}

extern "C" void kernel_launch(void* const* d_in, const int* in_sizes, int n_in,
                              void* d_out, int out_size, void* d_ws, size_t ws_size,
                              hipStream_t stream) {
  (void)in_sizes; (void)n_in; (void)ws_size; (void)out_size;
  const float* x     = (const float*)d_in[0];
  const float* noise = (const float*)d_in[1];
  const float* Wg    = (const float*)d_in[2];
  const float* bg    = (const float*)d_in[3];
  const float* Wn    = (const float*)d_in[4];
  const float* bn    = (const float*)d_in[5];
  const float* W1    = (const float*)d_in[6];
  const float* b1    = (const float*)d_in[7];
  const float* W2    = (const float*)d_in[8];
  const float* b2    = (const float*)d_in[9];
  float* out = (float*)d_out;

  char* ws = (char*)d_ws;
  size_t o = 0;
  auto take = [&](size_t b) { size_t r = o; o += (b + 255) & ~(size_t)255; return r; };
  int*   counts     = (int*)(ws + take(16 * 4));        // counts[8], zeroed
  int*   ntiles     = (int*)(ws + take(4));
  int4*  tiles      = (int4*)(ws + take(MAX_TILES * 16));
  int*   tok_e      = (int*)(ws + take((size_t)TP * 4));
  float* tok_w      = (float*)(ws + take((size_t)TP * 4));
  float* gp_tok     = (float*)(ws + take((size_t)T_TOK * 8 * 4));
  int*   pair_token = (int*)(ws + take((size_t)TP * 4));
  float* pair_w     = (float*)(ws + take((size_t)TP * 4));
  unsigned short* xb  = (unsigned short*)(ws + take((size_t)T_TOK * D_DIM * 2));
  unsigned short* w1t = (unsigned short*)(ws + take((size_t)E_EXP * H_DIM * D_DIM * 2));
  unsigned short* w2t = (unsigned short*)(ws + take((size_t)E_EXP * H_DIM * D_DIM * 2));
  unsigned short* hbuf = (unsigned short*)(ws + take((size_t)TP * H_DIM * 2));
  // total ws usage ~201 MB

  hipMemsetAsync(counts, 0, 16 * 4, stream);   // tiny; gating atomics need zeroed counts

  front_kernel<<<NGATE + NTRW1 + NZERO, 256, 0, stream>>>(
      W1, w1t, x, noise, Wg, bg, Wn, bn, tok_e, tok_w, gp_tok, counts, xb, out);
  finalize_kernel<<<1, 256, 0, stream>>>(counts, tiles, ntiles, tok_e, tok_w,
                                         pair_token, pair_w, gp_tok, out);
  ffn1_kernel<<<NTRW2 + MAX_TILES * (H_DIM / BN), 256, 0, stream>>>(
      xb, w1t, b1, pair_token, tiles, ntiles, hbuf, W2, w2t);
  ffn2_kernel<<<dim3(MAX_TILES * (D_DIM / BN)), 256, 0, stream>>>(
      hbuf, w2t, b2, pair_token, pair_w, tiles, ntiles, out);
}